// Round 4
// baseline (228.365 us; speedup 1.0000x reference)
//
#include <hip/hip_runtime.h>
#include <math.h>

#define NUM_CITIES 88
#define NUM_YEARS 6
#define N_ROWS 200000

#define TOT4 (N_ROWS * 22)        // 4,400,000 float4 elems in G/D/w
#define NT   (TOT4 / 4)           // 1,100,000 threads for main part; NT % 22 == 0
#define GBLK 4297                 // ceil(NT/256): 4297*256 = 1,100,032 (32 idle)

#define NQ4  (N_ROWS * NUM_YEARS / 4)   // 300,000 float4 elems in U/out
#define DTHREADS 75008                  // 293*256
#define DBLK 293

#define NBLK_TOT (GBLK + DBLK)    // 4590
#define NPART 92                  // 88 colsums + diff, r2, w2, neg
#define WS2_OFF (NBLK_TOT * NPART)

// Short-lived waves, copy-bench shape: each main-thread does exactly 4
// float4-triples at i, i+NT, i+2NT, i+3NT (4*NT == TOT4, no tail).
// i % 22 invariant across the 4 -> fixed 4-column group in registers.
__global__ __launch_bounds__(256) void loss_main(
    const float* __restrict__ G,
    const float* __restrict__ outm,
    const float* __restrict__ U,
    const float* __restrict__ D,
    const float* __restrict__ w,
    float* __restrict__ ws)
{
    __shared__ float scol[NUM_CITIES];
    __shared__ float ssum[4];

    const int tid = threadIdx.x;
    const int bid = blockIdx.x;

    if (tid < NUM_CITIES) scol[tid] = 0.f;
    if (tid < 4) ssum[tid] = 0.f;
    __syncthreads();

    float s_diff = 0.f, s_r2 = 0.f, s_w2 = 0.f, s_neg = 0.f;

    if (bid < GBLK) {
        const int i = bid * 256 + tid;
        const int c0 = (i % 22) * 4;
        float ca0 = 0.f, ca1 = 0.f, ca2 = 0.f, ca3 = 0.f;

        if (i < NT) {
            const float4* __restrict__ G4 = (const float4*)G;
            const float4* __restrict__ D4 = (const float4*)D;
            const float4* __restrict__ W4 = (const float4*)w;

            float4 g0 = G4[i + 0 * NT], g1 = G4[i + 1 * NT];
            float4 g2 = G4[i + 2 * NT], g3 = G4[i + 3 * NT];
            float4 d0 = D4[i + 0 * NT], d1 = D4[i + 1 * NT];
            float4 d2 = D4[i + 2 * NT], d3 = D4[i + 3 * NT];
            float4 v0 = W4[i + 0 * NT], v1 = W4[i + 1 * NT];
            float4 v2 = W4[i + 2 * NT], v3 = W4[i + 3 * NT];

#define ACC(g, d, v)                                                          \
            {                                                                 \
                ca0 += fabsf(g.x); ca1 += fabsf(g.y);                         \
                ca2 += fabsf(g.z); ca3 += fabsf(g.w);                         \
                float r0 = g.x - v.x * d.x, r1 = g.y - v.y * d.y;             \
                float r2 = g.z - v.z * d.z, r3 = g.w - v.w * d.w;             \
                s_r2 += r0 * r0 + r1 * r1 + r2 * r2 + r3 * r3;                \
                s_w2 += v.x * v.x + v.y * v.y + v.z * v.z + v.w * v.w;        \
                s_neg += fminf(g.x, 0.f) + fminf(g.y, 0.f)                    \
                       + fminf(g.z, 0.f) + fminf(g.w, 0.f);                   \
            }
            ACC(g0, d0, v0) ACC(g1, d1, v1) ACC(g2, d2, v2) ACC(g3, d3, v3)
#undef ACC
        }

        atomicAdd(&scol[c0 + 0], ca0);
        atomicAdd(&scol[c0 + 1], ca1);
        atomicAdd(&scol[c0 + 2], ca2);
        atomicAdd(&scol[c0 + 3], ca3);
    } else {
        // diff blocks: (U-out)^2 over cols 0..4 of 6, float4 with q%3 phase mask
        const float4* __restrict__ U4 = (const float4*)U;
        const float4* __restrict__ O4 = (const float4*)outm;
        const int dtid = (bid - GBLK) * 256 + tid;
        #pragma unroll 4
        for (int q = dtid; q < NQ4; q += DTHREADS) {
            float4 u = U4[q];
            float4 o = O4[q];
            float ex = u.x - o.x, ey = u.y - o.y;
            float ez = u.z - o.z, ew = u.w - o.w;
            int ph = q % 3;                 // 0: cols 0-3 | 1: 4,5,0,1 | 2: 2,3,4,5
            s_diff += ex * ex + ez * ez;
            s_diff += (ph == 1) ? 0.f : ey * ey;   // .y is col 5 when ph==1
            s_diff += (ph == 2) ? 0.f : ew * ew;   // .w is col 5 when ph==2
        }
    }

    // wave-level reduce of scalars, then one LDS atomic per wave
    for (int off = 32; off > 0; off >>= 1) {
        s_diff += __shfl_down(s_diff, off);
        s_r2   += __shfl_down(s_r2, off);
        s_w2   += __shfl_down(s_w2, off);
        s_neg  += __shfl_down(s_neg, off);
    }
    if ((tid & 63) == 0) {
        atomicAdd(&ssum[0], s_diff);
        atomicAdd(&ssum[1], s_r2);
        atomicAdd(&ssum[2], s_w2);
        atomicAdd(&ssum[3], s_neg);
    }
    __syncthreads();

    float* dst = ws + (size_t)bid * NPART;
    if (tid < NUM_CITIES)  dst[tid] = scol[tid];
    else if (tid < NPART)  dst[tid] = ssum[tid - NUM_CITIES];
}

// Stage A: block k sums partial k over all NBLK_TOT blocks -> ws[WS2_OFF + k]
__global__ __launch_bounds__(256) void loss_reduce(float* __restrict__ ws)
{
    const int k = blockIdx.x;
    const int t = threadIdx.x;
    float acc = 0.f;
    for (int b = t; b < NBLK_TOT; b += 256)
        acc += ws[(size_t)b * NPART + k];
    for (int off = 32; off > 0; off >>= 1) acc += __shfl_down(acc, off);
    __shared__ float s[4];
    if ((t & 63) == 0) s[t >> 6] = acc;
    __syncthreads();
    if (t == 0) ws[WS2_OFF + k] = s[0] + s[1] + s[2] + s[3];
}

// Stage B: loss = diff + 1e-4*sum(log(col)) + 100*r2 + 0.01*w2 + 100*neg
__global__ __launch_bounds__(128) void loss_finalize(
    const float* __restrict__ ws, float* __restrict__ out)
{
    __shared__ float sh[2];
    const int t = threadIdx.x;
    const float* ws2 = ws + WS2_OFF;

    float v = 0.f;
    if (t < NUM_CITIES)      v = 1e-4f * logf(ws2[t]);
    else if (t == 88)        v = ws2[88];           // diff
    else if (t == 89)        v = 100.f * ws2[89];   // r2 * sg^2/se^2
    else if (t == 90)        v = 0.01f * ws2[90];   // w2 * se^2/sw^2
    else if (t == 91)        v = 100.f * ws2[91];   // neg penalty

    for (int off = 32; off > 0; off >>= 1) v += __shfl_down(v, off);
    if (t == 0)  sh[0] = v;
    if (t == 64) sh[1] = v;
    __syncthreads();
    if (t == 0) out[0] = sh[0] + sh[1];
}

extern "C" void kernel_launch(void* const* d_in, const int* in_sizes, int n_in,
                              void* d_out, int out_size, void* d_ws, size_t ws_size,
                              hipStream_t stream) {
    const float* G    = (const float*)d_in[0];
    const float* outm = (const float*)d_in[1];
    const float* U    = (const float*)d_in[2];
    // d_in[3] = V, unused by the reference
    const float* D    = (const float*)d_in[4];
    const float* w    = (const float*)d_in[5];
    float* out = (float*)d_out;
    float* ws  = (float*)d_ws;

    loss_main<<<NBLK_TOT, 256, 0, stream>>>(G, outm, U, D, w, ws);
    loss_reduce<<<NPART, 256, 0, stream>>>(ws);
    loss_finalize<<<1, 128, 0, stream>>>(ws, out);
}

// Round 6
// 209.956 us; speedup vs baseline: 1.0877x; 1.0877x over previous
//
#include <hip/hip_runtime.h>
#include <math.h>

#define NUM_CITIES 88
#define NUM_YEARS 6
#define N_ROWS 200000

#define COL4 (NUM_CITIES / 4)            // 22 float4 groups per row
#define TOT4 (N_ROWS * COL4)             // 4,400,000 float4 elems in G/D/w
#define DIFF2 (N_ROWS * NUM_YEARS / 2)   // 600,000 float2 elems in U/out

#define NBLK 1936                        // NBLK*256 % 22 == 0
#define NTHREADS (NBLK * 256)            // 495616
#define NPART 92                         // 88 colsums + 4 scalars per block

// 8 guaranteed iterations per thread; tail (9th) for gtid < TAIL_CUT.
#define TAIL_CUT (TOT4 - 8 * NTHREADS)

#define WS2_OFF (NBLK * NPART)

// clang native vectors — required by __builtin_nontemporal_load
typedef float vf4 __attribute__((ext_vector_type(4)));
typedef float vf2 __attribute__((ext_vector_type(2)));

static __device__ __forceinline__ vf4 ldnt4(const float* p) {
    return __builtin_nontemporal_load((const vf4*)p);
}
static __device__ __forceinline__ vf2 ldnt2(const float* p) {
    return __builtin_nontemporal_load((const vf2*)p);
}

__global__ __launch_bounds__(256) void loss_main(
    const float* __restrict__ G,
    const float* __restrict__ outm,
    const float* __restrict__ U,
    const float* __restrict__ D,
    const float* __restrict__ w,
    float* __restrict__ ws)
{
    __shared__ float scol[NUM_CITIES];
    __shared__ float ssum[4];

    const int tid = threadIdx.x;
    const int gtid = blockIdx.x * blockDim.x + tid;
    const int c0 = (gtid % COL4) * 4;    // fixed column group (NTHREADS % 22 == 0)

    // ---- issue all 24 nontemporal loads for the 8 guaranteed iterations ----
    vf4 g0 = ldnt4(G + 4 * ((size_t)gtid + 0 * NTHREADS));
    vf4 g1 = ldnt4(G + 4 * ((size_t)gtid + 1 * NTHREADS));
    vf4 g2 = ldnt4(G + 4 * ((size_t)gtid + 2 * NTHREADS));
    vf4 g3 = ldnt4(G + 4 * ((size_t)gtid + 3 * NTHREADS));
    vf4 g4 = ldnt4(G + 4 * ((size_t)gtid + 4 * NTHREADS));
    vf4 g5 = ldnt4(G + 4 * ((size_t)gtid + 5 * NTHREADS));
    vf4 g6 = ldnt4(G + 4 * ((size_t)gtid + 6 * NTHREADS));
    vf4 g7 = ldnt4(G + 4 * ((size_t)gtid + 7 * NTHREADS));
    vf4 d0 = ldnt4(D + 4 * ((size_t)gtid + 0 * NTHREADS));
    vf4 d1 = ldnt4(D + 4 * ((size_t)gtid + 1 * NTHREADS));
    vf4 d2 = ldnt4(D + 4 * ((size_t)gtid + 2 * NTHREADS));
    vf4 d3 = ldnt4(D + 4 * ((size_t)gtid + 3 * NTHREADS));
    vf4 d4 = ldnt4(D + 4 * ((size_t)gtid + 4 * NTHREADS));
    vf4 d5 = ldnt4(D + 4 * ((size_t)gtid + 5 * NTHREADS));
    vf4 d6 = ldnt4(D + 4 * ((size_t)gtid + 6 * NTHREADS));
    vf4 d7 = ldnt4(D + 4 * ((size_t)gtid + 7 * NTHREADS));
    vf4 v0 = ldnt4(w + 4 * ((size_t)gtid + 0 * NTHREADS));
    vf4 v1 = ldnt4(w + 4 * ((size_t)gtid + 1 * NTHREADS));
    vf4 v2 = ldnt4(w + 4 * ((size_t)gtid + 2 * NTHREADS));
    vf4 v3 = ldnt4(w + 4 * ((size_t)gtid + 3 * NTHREADS));
    vf4 v4 = ldnt4(w + 4 * ((size_t)gtid + 4 * NTHREADS));
    vf4 v5 = ldnt4(w + 4 * ((size_t)gtid + 5 * NTHREADS));
    vf4 v6 = ldnt4(w + 4 * ((size_t)gtid + 6 * NTHREADS));
    vf4 v7 = ldnt4(w + 4 * ((size_t)gtid + 7 * NTHREADS));

    float ca0 = 0.f, ca1 = 0.f, ca2 = 0.f, ca3 = 0.f;
    float s_r2 = 0.f, s_w2 = 0.f, s_neg = 0.f;

#define ACC(g, d, v)                                                          \
    {                                                                         \
        ca0 += fabsf(g.x); ca1 += fabsf(g.y);                                 \
        ca2 += fabsf(g.z); ca3 += fabsf(g.w);                                 \
        float r0 = g.x - v.x * d.x, r1 = g.y - v.y * d.y;                     \
        float r2 = g.z - v.z * d.z, r3 = g.w - v.w * d.w;                     \
        s_r2 += r0 * r0 + r1 * r1 + r2 * r2 + r3 * r3;                        \
        s_w2 += v.x * v.x + v.y * v.y + v.z * v.z + v.w * v.w;                \
        s_neg += fminf(g.x, 0.f) + fminf(g.y, 0.f)                            \
               + fminf(g.z, 0.f) + fminf(g.w, 0.f);                          \
    }

    ACC(g0, d0, v0) ACC(g1, d1, v1) ACC(g2, d2, v2) ACC(g3, d3, v3)
    ACC(g4, d4, v4) ACC(g5, d5, v5) ACC(g6, d6, v6) ACC(g7, d7, v7)

    // tail iteration (stride preserves gtid % 22 -> same column group)
    if (gtid < TAIL_CUT) {
        vf4 g = ldnt4(G + 4 * ((size_t)gtid + 8 * NTHREADS));
        vf4 d = ldnt4(D + 4 * ((size_t)gtid + 8 * NTHREADS));
        vf4 v = ldnt4(w + 4 * ((size_t)gtid + 8 * NTHREADS));
        ACC(g, d, v)
    }
#undef ACC

    // ---- (U - out)^2 over first 5 of every 6 columns, float2-vectorized ----
    float s_diff = 0.f;
    {
        vf2 u = ldnt2(U + 2 * (size_t)gtid), o = ldnt2(outm + 2 * (size_t)gtid);
        float dx = u.x - o.x, dy = u.y - o.y;
        s_diff += dx * dx + ((gtid % 3 != 2) ? dy * dy : 0.f);
        const int i2 = gtid + NTHREADS;
        if (i2 < DIFF2) {
            vf2 u2 = ldnt2(U + 2 * (size_t)i2), o2 = ldnt2(outm + 2 * (size_t)i2);
            float ex = u2.x - o2.x, ey = u2.y - o2.y;
            s_diff += ex * ex + ((i2 % 3 != 2) ? ey * ey : 0.f);
        }
    }

    // ---- block-level reduction (LDS only) ----
    if (tid < NUM_CITIES) scol[tid] = 0.f;
    if (tid < 4) ssum[tid] = 0.f;
    __syncthreads();

    atomicAdd(&scol[c0 + 0], ca0);
    atomicAdd(&scol[c0 + 1], ca1);
    atomicAdd(&scol[c0 + 2], ca2);
    atomicAdd(&scol[c0 + 3], ca3);

    for (int off = 32; off > 0; off >>= 1) {
        s_diff += __shfl_down(s_diff, off);
        s_r2   += __shfl_down(s_r2, off);
        s_w2   += __shfl_down(s_w2, off);
        s_neg  += __shfl_down(s_neg, off);
    }
    if ((tid & 63) == 0) {
        atomicAdd(&ssum[0], s_diff);
        atomicAdd(&ssum[1], s_r2);
        atomicAdd(&ssum[2], s_w2);
        atomicAdd(&ssum[3], s_neg);
    }
    __syncthreads();

    float* dst = ws + (size_t)blockIdx.x * NPART;
    if (tid < NUM_CITIES) dst[tid] = scol[tid];
    else if (tid < NPART)  dst[tid] = ssum[tid - NUM_CITIES];
}

// Stage A: block k sums partial k over all NBLK blocks -> ws[WS2_OFF + k]
__global__ __launch_bounds__(256) void loss_reduce(float* __restrict__ ws)
{
    const int k = blockIdx.x;
    const int t = threadIdx.x;
    float acc = 0.f;
    for (int b = t; b < NBLK; b += 256)
        acc += ws[(size_t)b * NPART + k];
    for (int off = 32; off > 0; off >>= 1) acc += __shfl_down(acc, off);
    __shared__ float s[4];
    if ((t & 63) == 0) s[t >> 6] = acc;
    __syncthreads();
    if (t == 0) ws[WS2_OFF + k] = s[0] + s[1] + s[2] + s[3];
}

// Stage B: loss = diff + 1e-4*sum(log(col)) + 100*r2 + 0.01*w2 + 100*neg
__global__ __launch_bounds__(128) void loss_finalize(
    const float* __restrict__ ws, float* __restrict__ out)
{
    __shared__ float sh[2];
    const int t = threadIdx.x;
    const float* ws2 = ws + WS2_OFF;

    float v = 0.f;
    if (t < NUM_CITIES)      v = 1e-4f * logf(ws2[t]);
    else if (t == 88)        v = ws2[88];           // diff
    else if (t == 89)        v = 100.f * ws2[89];   // r2 * sg^2/se^2
    else if (t == 90)        v = 0.01f * ws2[90];   // w2 * se^2/sw^2
    else if (t == 91)        v = 100.f * ws2[91];   // neg penalty

    for (int off = 32; off > 0; off >>= 1) v += __shfl_down(v, off);
    if (t == 0)  sh[0] = v;
    if (t == 64) sh[1] = v;
    __syncthreads();
    if (t == 0) out[0] = sh[0] + sh[1];
}

extern "C" void kernel_launch(void* const* d_in, const int* in_sizes, int n_in,
                              void* d_out, int out_size, void* d_ws, size_t ws_size,
                              hipStream_t stream) {
    const float* G    = (const float*)d_in[0];
    const float* outm = (const float*)d_in[1];
    const float* U    = (const float*)d_in[2];
    // d_in[3] = V, unused by the reference
    const float* D    = (const float*)d_in[4];
    const float* w    = (const float*)d_in[5];
    float* out = (float*)d_out;
    float* ws  = (float*)d_ws;

    loss_main<<<NBLK, 256, 0, stream>>>(G, outm, U, D, w, ws);
    loss_reduce<<<NPART, 256, 0, stream>>>(ws);
    loss_finalize<<<1, 128, 0, stream>>>(ws, out);
}